// Round 5
// baseline (73.550 us; speedup 1.0000x reference)
//
#include <hip/hip_runtime.h>

typedef float f32x4 __attribute__((ext_vector_type(4)));
typedef short s16x8 __attribute__((ext_vector_type(8)));
typedef unsigned short u16;
typedef unsigned int u32;

// Problem constants
// B=4, T=320, U=80, D=512, INNER=512, VOCAB=6, MAX_RLE=50
// X rows: 1280 enc rows (b*320+t), then 320 dec rows (b*80+u). 1600 total.
// out: base [102400*6] then rle [102400*50], fp32.

__device__ __forceinline__ u16 f2bf(float f) {
  u32 u = __float_as_uint(f);
  u32 r = (u + 0x7FFFu + ((u >> 16) & 1u)) >> 16;  // RNE
  return (u16)r;
}

__device__ __forceinline__ float fast_tanh(float x) {
  x = fminf(15.f, fmaxf(-15.f, x));
  float e = __expf(2.f * x);
  return __fdividef(e - 1.f, e + 1.f);
}

// ---- prep 1: cast [enc;dec] (fp32) -> Xb (bf16), 819200 elems, 8/thread ----
__global__ void prep_cast_x(const float* __restrict__ enc,
                            const float* __restrict__ dec,
                            s16x8* __restrict__ Xb) {
  int idx = blockIdx.x * 256 + threadIdx.x;  // 0..102399
  long e = (long)idx * 8;
  const float* src = (e < 655360) ? (enc + e) : (dec + (e - 655360));
  f32x4 a = *(const f32x4*)src;
  f32x4 b = *(const f32x4*)(src + 4);
  s16x8 o;
  o[0] = (short)f2bf(a[0]); o[1] = (short)f2bf(a[1]);
  o[2] = (short)f2bf(a[2]); o[3] = (short)f2bf(a[3]);
  o[4] = (short)f2bf(b[0]); o[5] = (short)f2bf(b[1]);
  o[6] = (short)f2bf(b[2]); o[7] = (short)f2bf(b[3]);
  Xb[idx] = o;
}

// ---- prep 2: fragment-pack W_f -> WfF[part][nt 0..31][kk 0..15][lane][j] ----
__global__ void prep_wf(const float* __restrict__ Wf, u16* __restrict__ WfF) {
  for (int idx = blockIdx.x * 256 + threadIdx.x; idx < 524288;
       idx += gridDim.x * 256) {
    int j = idx & 7;
    int lane = (idx >> 3) & 63;
    int kk = (idx >> 9) & 15;
    int nt = (idx >> 13) & 31;
    int part = idx >> 18;
    int n = nt * 16 + (lane & 15);
    int k = part * 512 + kk * 32 + ((lane >> 4) << 3) + j;
    WfF[idx] = f2bf(Wf[n * 1024 + k]);
  }
}

// ---- prep 3: fragment-pack [W_base;W_rle;0] -> WoF[nt 0..3][ks 0..15][lane][j], + bias_cat[64]
__global__ void prep_wo(const float* __restrict__ Wb, const float* __restrict__ bb,
                        const float* __restrict__ Wr, const float* __restrict__ br,
                        u16* __restrict__ WoF, float* __restrict__ bias_cat) {
  int idx = blockIdx.x * 256 + threadIdx.x;
  if (idx < 32768) {
    int j = idx & 7;
    int lane = (idx >> 3) & 63;
    int ks = (idx >> 9) & 15;
    int nt = idx >> 13;
    int v = nt * 16 + (lane & 15);
    int k = ks * 32 + ((lane >> 4) << 3) + j;
    float val = (v < 6) ? Wb[v * 512 + k] : (v < 56 ? Wr[(v - 6) * 512 + k] : 0.f);
    WoF[idx] = f2bf(val);
  }
  if (blockIdx.x == 0 && threadIdx.x < 64) {
    int v = threadIdx.x;
    bias_cat[v] = (v < 6) ? bb[v] : (v < 56 ? br[v - 6] : 0.f);
  }
}

// ---- E-GEMM: Ebf[1280][512] = enc*Wf[:, :512]^T + b_f ; Dc[320][512] = dec*Wf[:,512:]^T
__global__ __launch_bounds__(256) void egemm(const s16x8* __restrict__ Xb,
                                             const s16x8* __restrict__ WfF,
                                             const float* __restrict__ b_f,
                                             float* __restrict__ Ebf,
                                             float* __restrict__ Dc) {
  int ms = blockIdx.x >> 3;   // 0..24
  int ns = blockIdx.x & 7;    // 0..7
  int w = threadIdx.x >> 6, l = threadIdx.x & 63;
  int r0 = ms * 64 + w * 16;
  int part = (r0 >= 1280) ? 1 : 0;
  int n0 = ns * 64;
  int lrow = r0 + (l & 15);
  int khi = (l >> 4) << 3;  // 0,8,16,24
  f32x4 acc[4] = {};
#pragma unroll
  for (int kk = 0; kk < 16; ++kk) {
    s16x8 a = Xb[lrow * 64 + kk * 4 + (khi >> 3)];
#pragma unroll
    for (int nt = 0; nt < 4; ++nt) {
      int ntg = ns * 4 + nt;
      s16x8 bf = WfF[((part * 32 + ntg) * 16 + kk) * 64 + l];
      acc[nt] = __builtin_amdgcn_mfma_f32_16x16x32_bf16(a, bf, acc[nt], 0, 0, 0);
    }
  }
#pragma unroll
  for (int nt = 0; nt < 4; ++nt) {
    int n = n0 + nt * 16 + (l & 15);
    float bias = part ? 0.f : b_f[n];
#pragma unroll
    for (int q = 0; q < 4; ++q) {
      int row = r0 + ((l >> 4) << 2) + q;
      float val = acc[nt][q] + bias;
      if (part) Dc[(row - 1280) * 512 + n] = val;
      else      Ebf[row * 512 + n] = val;
    }
  }
}

// ---- main: block = (b,t, u-half). half 0: rows 0..47 (3 m-tiles); half 1: rows 48..79 (2 m-tiles).
// grid 2560, block 256 (4 waves; wave w owns n-tile w). Numerics IDENTICAL to the R1 passing kernel.
__global__ __launch_bounds__(256) void joint_main(const float* __restrict__ Ebf,
                                                  const float* __restrict__ Dc,
                                                  const s16x8* __restrict__ WoF,
                                                  const float* __restrict__ bias_cat,
                                                  float* __restrict__ out) {
  __shared__ float e_s[512];
  __shared__ s16x8 h_s[48 * 16];  // [u_local][16 units of 16B], unit XOR-swizzled by (u&7)
  int bid = blockIdx.x;
  int bt = bid >> 1, half = bid & 1;
  int b = bt / 320;
  int u0 = half ? 48 : 0;
  int nr = half ? 2 : 3;          // m-tiles this block
  int tid = threadIdx.x;
  int w = tid >> 6, l = tid & 63;

  e_s[tid] = Ebf[bt * 512 + tid];
  e_s[tid + 256] = Ebf[bt * 512 + 256 + tid];
  const float* DcB = Dc + b * 80 * 512 + u0 * 512;
  int v = w * 16 + (l & 15);
  float bias_v = bias_cat[v];
  f32x4 acc[3] = {};
  __syncthreads();

  for (int c = 0; c < 4; ++c) {
    // h-compute: nr*256 slots of (u_local, k8) -> 8 bf16 each
    for (int s5 = 0; s5 < nr; ++s5) {
      int s = tid + s5 * 256;
      int ul = s >> 4, k8 = s & 15;
      int gk = c * 128 + k8 * 8;
      f32x4 d0 = *(const f32x4*)(DcB + ul * 512 + gk);
      f32x4 d1 = *(const f32x4*)(DcB + ul * 512 + gk + 4);
      f32x4 e0 = *(const f32x4*)(e_s + gk);
      f32x4 e1 = *(const f32x4*)(e_s + gk + 4);
      s16x8 hv;
#pragma unroll
      for (int j = 0; j < 4; ++j) {
        hv[j]     = (short)f2bf(fast_tanh(e0[j] + d0[j]));
        hv[j + 4] = (short)f2bf(fast_tanh(e1[j] + d1[j]));
      }
      h_s[ul * 16 + (k8 ^ (ul & 7))] = hv;
    }
    __syncthreads();

    // MFMA: wave w = n-tile w; nr m-tiles x 4 k-steps
    s16x8 bfr[4];
#pragma unroll
    for (int kk = 0; kk < 4; ++kk)
      bfr[kk] = WoF[(w * 16 + c * 4 + kk) * 64 + l];
#pragma unroll
    for (int kk = 0; kk < 4; ++kk) {
      int unit = kk * 4 + (l >> 4);
#pragma unroll
      for (int mt = 0; mt < 3; ++mt) {
        if (mt < nr) {
          int ur = mt * 16 + (l & 15);
          s16x8 a = h_s[ur * 16 + (unit ^ (ur & 7))];
          acc[mt] = __builtin_amdgcn_mfma_f32_16x16x32_bf16(a, bfr[kk], acc[mt], 0, 0, 0);
        }
      }
    }
    __syncthreads();
  }

  // epilogue: C/D map row=(l>>4)*4+q (u), col=l&15 (v)
  long pbase = (long)bt * 80 + u0;
#pragma unroll
  for (int mt = 0; mt < 3; ++mt) {
    if (mt < nr) {
#pragma unroll
      for (int q = 0; q < 4; ++q) {
        int u = mt * 16 + ((l >> 4) << 2) + q;
        long p = pbase + u;
        float val = acc[mt][q] + bias_v;
        if (v < 6)       out[p * 6 + v] = val;
        else if (v < 56) out[614400 + p * 50 + (v - 6)] = val;
      }
    }
  }
}

extern "C" void kernel_launch(void* const* d_in, const int* in_sizes, int n_in,
                              void* d_out, int out_size, void* d_ws, size_t ws_size,
                              hipStream_t stream) {
  (void)in_sizes; (void)n_in; (void)out_size; (void)ws_size;
  const float* enc = (const float*)d_in[0];
  const float* dec = (const float*)d_in[1];
  const float* Wf  = (const float*)d_in[2];
  const float* bf  = (const float*)d_in[3];
  const float* Wb  = (const float*)d_in[4];
  const float* bb  = (const float*)d_in[5];
  const float* Wr  = (const float*)d_in[6];
  const float* br  = (const float*)d_in[7];
  float* out = (float*)d_out;
  char* ws = (char*)d_ws;

  s16x8* Xb     = (s16x8*)(ws);               // 1,638,400 B
  u16*   WfF    = (u16*)(ws + 1638400);       // 1,048,576 B
  u16*   WoF    = (u16*)(ws + 2686976);       //    65,536 B
  float* biasC  = (float*)(ws + 2752512);     //       256 B
  float* Ebf    = (float*)(ws + 2752768);     // 2,621,440 B
  float* Dc     = (float*)(ws + 5374208);     //   655,360 B
  // total 6,029,568 B of d_ws used

  prep_cast_x<<<400, 256, 0, stream>>>(enc, dec, Xb);
  prep_wf<<<512, 256, 0, stream>>>(Wf, WfF);
  prep_wo<<<128, 256, 0, stream>>>(Wb, bb, Wr, br, WoF, biasC);
  egemm<<<200, 256, 0, stream>>>(Xb, (const s16x8*)WfF, bf, Ebf, Dc);
  joint_main<<<2560, 256, 0, stream>>>(Ebf, Dc, (const s16x8*)WoF, biasC, out);
}

// Round 6
// 65.380 us; speedup vs baseline: 1.1250x; 1.1250x over previous
//
#include <hip/hip_runtime.h>

typedef float f32x4 __attribute__((ext_vector_type(4)));
typedef short s16x8 __attribute__((ext_vector_type(8)));
typedef unsigned short u16;
typedef unsigned int u32;

// Problem constants
// B=4, T=320, U=80, D=512, INNER=512, VOCAB=6, MAX_RLE=50
// X rows: 1280 enc rows (b*320+t), then 320 dec rows (b*80+u). 1600 total.
// out: base [102400*6] then rle [102400*50], fp32.

__device__ __forceinline__ u16 f2bf(float f) {
  u32 u = __float_as_uint(f);
  u32 r = (u + 0x7FFFu + ((u >> 16) & 1u)) >> 16;  // RNE
  return (u16)r;
}

// Packed f32x2 -> bf16x2 via explicit ISA op (T12 recipe, HW-verified m214v22).
// %1 -> low half, %2 -> high half.
__device__ __forceinline__ u32 cvt_pk_bf16(float lo, float hi) {
  u32 r;
  asm("v_cvt_pk_bf16_f32 %0, %1, %2" : "=v"(r) : "v"(lo), "v"(hi));
  return r;
}

__device__ __forceinline__ float fast_tanh(float x) {
  x = fminf(15.f, fmaxf(-15.f, x));
  float e = __expf(2.f * x);
  return __fdividef(e - 1.f, e + 1.f);
}

// ---- fused prep: [0,400) cast X; [400,2448) pack W_f; [2448,2576) pack W_out + bias ----
__global__ void prep_all(const float* __restrict__ enc, const float* __restrict__ dec,
                         s16x8* __restrict__ Xb,
                         const float* __restrict__ Wf, u16* __restrict__ WfF,
                         const float* __restrict__ Wb, const float* __restrict__ bb,
                         const float* __restrict__ Wr, const float* __restrict__ br,
                         u16* __restrict__ WoF, float* __restrict__ bias_cat) {
  int bx = blockIdx.x;
  int tid = threadIdx.x;
  if (bx < 400) {
    // cast [enc;dec] (fp32) -> Xb (bf16), 819200 elems, 8/thread
    int idx = bx * 256 + tid;  // 0..102399
    long e = (long)idx * 8;
    const float* src = (e < 655360) ? (enc + e) : (dec + (e - 655360));
    f32x4 a = *(const f32x4*)src;
    f32x4 b = *(const f32x4*)(src + 4);
    s16x8 o;
    o[0] = (short)f2bf(a[0]); o[1] = (short)f2bf(a[1]);
    o[2] = (short)f2bf(a[2]); o[3] = (short)f2bf(a[3]);
    o[4] = (short)f2bf(b[0]); o[5] = (short)f2bf(b[1]);
    o[6] = (short)f2bf(b[2]); o[7] = (short)f2bf(b[3]);
    Xb[idx] = o;
  } else if (bx < 2448) {
    // fragment-pack W_f -> WfF[part][nt 0..31][kk 0..15][lane][j]
    int idx = (bx - 400) * 256 + tid;  // 0..524287
    int j = idx & 7;
    int lane = (idx >> 3) & 63;
    int kk = (idx >> 9) & 15;
    int nt = (idx >> 13) & 31;
    int part = idx >> 18;
    int n = nt * 16 + (lane & 15);
    int k = part * 512 + kk * 32 + ((lane >> 4) << 3) + j;
    WfF[idx] = f2bf(Wf[n * 1024 + k]);
  } else {
    // fragment-pack [W_base;W_rle;0] -> WoF[nt 0..3][ks 0..15][lane][j], + bias_cat[64]
    int idx = (bx - 2448) * 256 + tid;  // 0..32767
    int j = idx & 7;
    int lane = (idx >> 3) & 63;
    int ks = (idx >> 9) & 15;
    int nt = idx >> 13;
    int v = nt * 16 + (lane & 15);
    int k = ks * 32 + ((lane >> 4) << 3) + j;
    float val = (v < 6) ? Wb[v * 512 + k] : (v < 56 ? Wr[(v - 6) * 512 + k] : 0.f);
    WoF[idx] = f2bf(val);
    if (bx == 2448 && tid < 64) {
      int vv = tid;
      bias_cat[vv] = (vv < 6) ? bb[vv] : (vv < 56 ? br[vv - 6] : 0.f);
    }
  }
}

// ---- E-GEMM: Ebf[1280][512] = enc*Wf[:, :512]^T + b_f ; Dc[320][512] = dec*Wf[:,512:]^T
__global__ __launch_bounds__(256) void egemm(const s16x8* __restrict__ Xb,
                                             const s16x8* __restrict__ WfF,
                                             const float* __restrict__ b_f,
                                             float* __restrict__ Ebf,
                                             float* __restrict__ Dc) {
  int ms = blockIdx.x >> 3;   // 0..24
  int ns = blockIdx.x & 7;    // 0..7
  int w = threadIdx.x >> 6, l = threadIdx.x & 63;
  int r0 = ms * 64 + w * 16;
  int part = (r0 >= 1280) ? 1 : 0;
  int n0 = ns * 64;
  int lrow = r0 + (l & 15);
  int khi = (l >> 4) << 3;  // 0,8,16,24
  f32x4 acc[4] = {};
#pragma unroll
  for (int kk = 0; kk < 16; ++kk) {
    s16x8 a = Xb[lrow * 64 + kk * 4 + (khi >> 3)];
#pragma unroll
    for (int nt = 0; nt < 4; ++nt) {
      int ntg = ns * 4 + nt;
      s16x8 bf = WfF[((part * 32 + ntg) * 16 + kk) * 64 + l];
      acc[nt] = __builtin_amdgcn_mfma_f32_16x16x32_bf16(a, bf, acc[nt], 0, 0, 0);
    }
  }
#pragma unroll
  for (int nt = 0; nt < 4; ++nt) {
    int n = n0 + nt * 16 + (l & 15);
    float bias = part ? 0.f : b_f[n];
#pragma unroll
    for (int q = 0; q < 4; ++q) {
      int row = r0 + ((l >> 4) << 2) + q;
      float val = acc[nt][q] + bias;
      if (part) Dc[(row - 1280) * 512 + n] = val;
      else      Ebf[row * 512 + n] = val;
    }
  }
}

// ---- main: block = (b,t, u-half). half 0: rows 0..47 (3 m-tiles); half 1: rows 48..79 (2 m-tiles).
// grid 2560, block 256 (4 waves; wave w owns n-tile w).
// Only change vs passing R5: h-cast via inline-asm v_cvt_pk_bf16_f32.
__global__ __launch_bounds__(256) void joint_main(const float* __restrict__ Ebf,
                                                  const float* __restrict__ Dc,
                                                  const s16x8* __restrict__ WoF,
                                                  const float* __restrict__ bias_cat,
                                                  float* __restrict__ out) {
  __shared__ float e_s[512];
  __shared__ s16x8 h_s[48 * 16];  // [u_local][16 units of 16B], unit XOR-swizzled by (u&7)
  int bid = blockIdx.x;
  int bt = bid >> 1, half = bid & 1;
  int b = bt / 320;
  int u0 = half ? 48 : 0;
  int nr = half ? 2 : 3;          // m-tiles this block
  int tid = threadIdx.x;
  int w = tid >> 6, l = tid & 63;

  e_s[tid] = Ebf[bt * 512 + tid];
  e_s[tid + 256] = Ebf[bt * 512 + 256 + tid];
  const float* DcB = Dc + b * 80 * 512 + u0 * 512;
  int v = w * 16 + (l & 15);
  float bias_v = bias_cat[v];
  f32x4 acc[3] = {};
  __syncthreads();

  for (int c = 0; c < 4; ++c) {
    // h-compute: nr*256 slots of (u_local, k8) -> 8 bf16 each
    for (int s5 = 0; s5 < nr; ++s5) {
      int s = tid + s5 * 256;
      int ul = s >> 4, k8 = s & 15;
      int gk = c * 128 + k8 * 8;
      f32x4 d0 = *(const f32x4*)(DcB + ul * 512 + gk);
      f32x4 d1 = *(const f32x4*)(DcB + ul * 512 + gk + 4);
      f32x4 e0 = *(const f32x4*)(e_s + gk);
      f32x4 e1 = *(const f32x4*)(e_s + gk + 4);
      float t[8];
#pragma unroll
      for (int j = 0; j < 4; ++j) {
        t[j]     = fast_tanh(e0[j] + d0[j]);
        t[j + 4] = fast_tanh(e1[j] + d1[j]);
      }
      union { s16x8 vv; u32 ww[4]; } hb;
#pragma unroll
      for (int k = 0; k < 4; ++k)
        hb.ww[k] = cvt_pk_bf16(t[2 * k], t[2 * k + 1]);
      h_s[ul * 16 + (k8 ^ (ul & 7))] = hb.vv;
    }
    __syncthreads();

    // MFMA: wave w = n-tile w; nr m-tiles x 4 k-steps
    s16x8 bfr[4];
#pragma unroll
    for (int kk = 0; kk < 4; ++kk)
      bfr[kk] = WoF[(w * 16 + c * 4 + kk) * 64 + l];
#pragma unroll
    for (int kk = 0; kk < 4; ++kk) {
      int unit = kk * 4 + (l >> 4);
#pragma unroll
      for (int mt = 0; mt < 3; ++mt) {
        if (mt < nr) {
          int ur = mt * 16 + (l & 15);
          s16x8 a = h_s[ur * 16 + (unit ^ (ur & 7))];
          acc[mt] = __builtin_amdgcn_mfma_f32_16x16x32_bf16(a, bfr[kk], acc[mt], 0, 0, 0);
        }
      }
    }
    __syncthreads();
  }

  // epilogue: C/D map row=(l>>4)*4+q (u), col=l&15 (v)
  long pbase = (long)bt * 80 + u0;
#pragma unroll
  for (int mt = 0; mt < 3; ++mt) {
    if (mt < nr) {
#pragma unroll
      for (int q = 0; q < 4; ++q) {
        int u = mt * 16 + ((l >> 4) << 2) + q;
        long p = pbase + u;
        float val = acc[mt][q] + bias_v;
        if (v < 6)       out[p * 6 + v] = val;
        else if (v < 56) out[614400 + p * 50 + (v - 6)] = val;
      }
    }
  }
}

extern "C" void kernel_launch(void* const* d_in, const int* in_sizes, int n_in,
                              void* d_out, int out_size, void* d_ws, size_t ws_size,
                              hipStream_t stream) {
  (void)in_sizes; (void)n_in; (void)out_size; (void)ws_size;
  const float* enc = (const float*)d_in[0];
  const float* dec = (const float*)d_in[1];
  const float* Wf  = (const float*)d_in[2];
  const float* bf  = (const float*)d_in[3];
  const float* Wb  = (const float*)d_in[4];
  const float* bb  = (const float*)d_in[5];
  const float* Wr  = (const float*)d_in[6];
  const float* br  = (const float*)d_in[7];
  float* out = (float*)d_out;
  char* ws = (char*)d_ws;

  s16x8* Xb     = (s16x8*)(ws);               // 1,638,400 B
  u16*   WfF    = (u16*)(ws + 1638400);       // 1,048,576 B
  u16*   WoF    = (u16*)(ws + 2686976);       //    65,536 B
  float* biasC  = (float*)(ws + 2752512);     //       256 B
  float* Ebf    = (float*)(ws + 2752768);     // 2,621,440 B
  float* Dc     = (float*)(ws + 5374208);     //   655,360 B
  // total 6,029,568 B of d_ws used

  prep_all<<<2576, 256, 0, stream>>>(enc, dec, Xb, Wf, WfF, Wb, bb, Wr, br, WoF, biasC);
  egemm<<<200, 256, 0, stream>>>(Xb, (const s16x8*)WfF, bf, Ebf, Dc);
  joint_main<<<2560, 256, 0, stream>>>(Ebf, Dc, (const s16x8*)WoF, biasC, out);
}

// Round 7
// 60.684 us; speedup vs baseline: 1.2120x; 1.0774x over previous
//
#include <hip/hip_runtime.h>

typedef float f32x4 __attribute__((ext_vector_type(4)));
typedef short s16x8 __attribute__((ext_vector_type(8)));
typedef unsigned short u16;
typedef unsigned int u32;

// Problem constants
// B=4, T=320, U=80, D=512, INNER=512, VOCAB=6, MAX_RLE=50
// X rows: 1280 enc rows (b*320+t), then 320 dec rows (b*80+u). 1600 total.
// out: base [102400*6] then rle [102400*50], fp32.

__device__ __forceinline__ u16 f2bf(float f) {
  u32 u = __float_as_uint(f);
  u32 r = (u + 0x7FFFu + ((u >> 16) & 1u)) >> 16;  // RNE
  return (u16)r;
}

// Packed f32x2 -> bf16x2 via explicit ISA op (T12 recipe, HW-verified m214v22;
// R6-proven bit-identical to f2bf). %1 -> low half, %2 -> high half.
__device__ __forceinline__ u32 cvt_pk_bf16(float lo, float hi) {
  u32 r;
  asm("v_cvt_pk_bf16_f32 %0, %1, %2" : "=v"(r) : "v"(lo), "v"(hi));
  return r;
}

__device__ __forceinline__ float fast_tanh(float x) {
  x = fminf(15.f, fmaxf(-15.f, x));
  float e = __expf(2.f * x);
  return __fdividef(e - 1.f, e + 1.f);
}

// ---- fused prep: [0,400) cast X; [400,2448) pack W_f; [2448,2576) pack W_out + bias ----
__global__ void prep_all(const float* __restrict__ enc, const float* __restrict__ dec,
                         s16x8* __restrict__ Xb,
                         const float* __restrict__ Wf, u16* __restrict__ WfF,
                         const float* __restrict__ Wb, const float* __restrict__ bb,
                         const float* __restrict__ Wr, const float* __restrict__ br,
                         u16* __restrict__ WoF, float* __restrict__ bias_cat) {
  int bx = blockIdx.x;
  int tid = threadIdx.x;
  if (bx < 400) {
    int idx = bx * 256 + tid;  // 0..102399
    long e = (long)idx * 8;
    const float* src = (e < 655360) ? (enc + e) : (dec + (e - 655360));
    f32x4 a = *(const f32x4*)src;
    f32x4 b = *(const f32x4*)(src + 4);
    s16x8 o;
    o[0] = (short)f2bf(a[0]); o[1] = (short)f2bf(a[1]);
    o[2] = (short)f2bf(a[2]); o[3] = (short)f2bf(a[3]);
    o[4] = (short)f2bf(b[0]); o[5] = (short)f2bf(b[1]);
    o[6] = (short)f2bf(b[2]); o[7] = (short)f2bf(b[3]);
    Xb[idx] = o;
  } else if (bx < 2448) {
    int idx = (bx - 400) * 256 + tid;  // 0..524287
    int j = idx & 7;
    int lane = (idx >> 3) & 63;
    int kk = (idx >> 9) & 15;
    int nt = (idx >> 13) & 31;
    int part = idx >> 18;
    int n = nt * 16 + (lane & 15);
    int k = part * 512 + kk * 32 + ((lane >> 4) << 3) + j;
    WfF[idx] = f2bf(Wf[n * 1024 + k]);
  } else {
    int idx = (bx - 2448) * 256 + tid;  // 0..32767
    int j = idx & 7;
    int lane = (idx >> 3) & 63;
    int ks = (idx >> 9) & 15;
    int nt = idx >> 13;
    int v = nt * 16 + (lane & 15);
    int k = ks * 32 + ((lane >> 4) << 3) + j;
    float val = (v < 6) ? Wb[v * 512 + k] : (v < 56 ? Wr[(v - 6) * 512 + k] : 0.f);
    WoF[idx] = f2bf(val);
    if (bx == 2448 && tid < 64) {
      int vv = tid;
      bias_cat[vv] = (vv < 6) ? bb[vv] : (vv < 56 ? br[vv - 6] : 0.f);
    }
  }
}

// ---- E-GEMM: Ebf[1280][512] = enc*Wf[:, :512]^T + b_f ; Dc[320][512] = dec*Wf[:,512:]^T
__global__ __launch_bounds__(256) void egemm(const s16x8* __restrict__ Xb,
                                             const s16x8* __restrict__ WfF,
                                             const float* __restrict__ b_f,
                                             float* __restrict__ Ebf,
                                             float* __restrict__ Dc) {
  int ms = blockIdx.x >> 3;   // 0..24
  int ns = blockIdx.x & 7;    // 0..7
  int w = threadIdx.x >> 6, l = threadIdx.x & 63;
  int r0 = ms * 64 + w * 16;
  int part = (r0 >= 1280) ? 1 : 0;
  int n0 = ns * 64;
  int lrow = r0 + (l & 15);
  int khi = (l >> 4) << 3;  // 0,8,16,24
  f32x4 acc[4] = {};
#pragma unroll
  for (int kk = 0; kk < 16; ++kk) {
    s16x8 a = Xb[lrow * 64 + kk * 4 + (khi >> 3)];
#pragma unroll
    for (int nt = 0; nt < 4; ++nt) {
      int ntg = ns * 4 + nt;
      s16x8 bf = WfF[((part * 32 + ntg) * 16 + kk) * 64 + l];
      acc[nt] = __builtin_amdgcn_mfma_f32_16x16x32_bf16(a, bf, acc[nt], 0, 0, 0);
    }
  }
#pragma unroll
  for (int nt = 0; nt < 4; ++nt) {
    int n = n0 + nt * 16 + (l & 15);
    float bias = part ? 0.f : b_f[n];
#pragma unroll
    for (int q = 0; q < 4; ++q) {
      int row = r0 + ((l >> 4) << 2) + q;
      float val = acc[nt][q] + bias;
      if (part) Dc[(row - 1280) * 512 + n] = val;
      else      Ebf[row * 512 + n] = val;
    }
  }
}

// ---- main body, software-pipelined (register prefetch of Dc one slot ahead,
// bfr prefetch at tanh-phase start, E read per-chunk direct from global).
// Numerics identical to R6 (same adds, same fast_tanh, same cvt_pk, same MFMA order).
template <int NR>
__device__ __forceinline__ void jbody(s16x8* h_s,
                                      const float* __restrict__ Ebf,
                                      const float* __restrict__ Dc,
                                      const s16x8* __restrict__ WoF,
                                      const float* __restrict__ bias_cat,
                                      float* __restrict__ out, int bt, int u0) {
  int b = bt / 320;
  const float* DcB = Dc + (b * 80 + u0) * 512;
  const float* Eb  = Ebf + bt * 512;
  int tid = threadIdx.x, w = tid >> 6, l = tid & 63;
  int k8  = tid & 15;     // thread's fixed k8 slot
  int ul0 = tid >> 4;     // 0..15; slot s5 adds 16
  const float* dbase = DcB + ul0 * 512 + k8 * 8;
  const float* ebase = Eb + k8 * 8;
  int v = w * 16 + (l & 15);
  float bias_v = bias_cat[v];
  f32x4 acc[NR] = {};

  // prologue: prefetch chunk 0 slot 0 + chunk 0 E
  f32x4 d0 = *(const f32x4*)(dbase);
  f32x4 d1 = *(const f32x4*)(dbase + 4);
  f32x4 e0 = *(const f32x4*)(ebase);
  f32x4 e1 = *(const f32x4*)(ebase + 4);

#pragma unroll
  for (int c = 0; c < 4; ++c) {
    // bfr prefetch for this chunk's MFMA phase (hidden under tanh)
    s16x8 bfr[4];
#pragma unroll
    for (int kk = 0; kk < 4; ++kk)
      bfr[kk] = WoF[(w * 16 + c * 4 + kk) * 64 + l];
    // E prefetch for next chunk
    f32x4 ne0, ne1;
    if (c < 3) {
      ne0 = *(const f32x4*)(ebase + (c + 1) * 128);
      ne1 = *(const f32x4*)(ebase + (c + 1) * 128 + 4);
    }
#pragma unroll
    for (int s5 = 0; s5 < NR; ++s5) {
      // prefetch next slot's Dc pair (crosses the barrier+MFMA at chunk end)
      f32x4 nd0, nd1;
      if (!(c == 3 && s5 == NR - 1)) {
        int nc  = (s5 == NR - 1) ? c + 1 : c;
        int ns5 = (s5 == NR - 1) ? 0 : s5 + 1;
        const float* np = dbase + ns5 * (16 * 512) + nc * 128;
        nd0 = *(const f32x4*)(np);
        nd1 = *(const f32x4*)(np + 4);
      }
      // consume current slot
      float t[8];
#pragma unroll
      for (int j = 0; j < 4; ++j) {
        t[j]     = fast_tanh(e0[j] + d0[j]);
        t[j + 4] = fast_tanh(e1[j] + d1[j]);
      }
      union { s16x8 vv; u32 ww[4]; } hb;
#pragma unroll
      for (int k = 0; k < 4; ++k)
        hb.ww[k] = cvt_pk_bf16(t[2 * k], t[2 * k + 1]);
      int ul = ul0 + s5 * 16;
      h_s[ul * 16 + (k8 ^ (ul & 7))] = hb.vv;
      d0 = nd0; d1 = nd1;
    }
    __syncthreads();
    // MFMA: wave w = n-tile w; NR m-tiles x 4 k-steps
#pragma unroll
    for (int kk = 0; kk < 4; ++kk) {
      int unit = kk * 4 + (l >> 4);
#pragma unroll
      for (int mt = 0; mt < NR; ++mt) {
        int ur = mt * 16 + (l & 15);
        s16x8 a = h_s[ur * 16 + (unit ^ (ur & 7))];
        acc[mt] = __builtin_amdgcn_mfma_f32_16x16x32_bf16(a, bfr[kk], acc[mt], 0, 0, 0);
      }
    }
    __syncthreads();
    if (c < 3) { e0 = ne0; e1 = ne1; }
  }

  // epilogue: C/D map row=(l>>4)*4+q (u), col=l&15 (v)
  long pbase = (long)bt * 80 + u0;
#pragma unroll
  for (int mt = 0; mt < NR; ++mt) {
#pragma unroll
    for (int q = 0; q < 4; ++q) {
      int u = mt * 16 + ((l >> 4) << 2) + q;
      long p = pbase + u;
      float val = acc[mt][q] + bias_v;
      if (v < 6)       out[p * 6 + v] = val;
      else if (v < 56) out[614400 + p * 50 + (v - 6)] = val;
    }
  }
}

// grid 2560: block = (b,t, u-half). half 0: rows 0..47 (NR=3); half 1: rows 48..79 (NR=2).
__global__ __launch_bounds__(256) void joint_main(const float* __restrict__ Ebf,
                                                  const float* __restrict__ Dc,
                                                  const s16x8* __restrict__ WoF,
                                                  const float* __restrict__ bias_cat,
                                                  float* __restrict__ out) {
  __shared__ s16x8 h_s[48 * 16];  // [u_local][16 units of 16B], unit XOR-swizzled by (u&7)
  int bid = blockIdx.x;
  int bt = bid >> 1, half = bid & 1;
  if (half) jbody<2>(h_s, Ebf, Dc, WoF, bias_cat, out, bt, 48);
  else      jbody<3>(h_s, Ebf, Dc, WoF, bias_cat, out, bt, 0);
}

extern "C" void kernel_launch(void* const* d_in, const int* in_sizes, int n_in,
                              void* d_out, int out_size, void* d_ws, size_t ws_size,
                              hipStream_t stream) {
  (void)in_sizes; (void)n_in; (void)out_size; (void)ws_size;
  const float* enc = (const float*)d_in[0];
  const float* dec = (const float*)d_in[1];
  const float* Wf  = (const float*)d_in[2];
  const float* bf  = (const float*)d_in[3];
  const float* Wb  = (const float*)d_in[4];
  const float* bb  = (const float*)d_in[5];
  const float* Wr  = (const float*)d_in[6];
  const float* br  = (const float*)d_in[7];
  float* out = (float*)d_out;
  char* ws = (char*)d_ws;

  s16x8* Xb     = (s16x8*)(ws);               // 1,638,400 B
  u16*   WfF    = (u16*)(ws + 1638400);       // 1,048,576 B
  u16*   WoF    = (u16*)(ws + 2686976);       //    65,536 B
  float* biasC  = (float*)(ws + 2752512);     //       256 B
  float* Ebf    = (float*)(ws + 2752768);     // 2,621,440 B
  float* Dc     = (float*)(ws + 5374208);     //   655,360 B
  // total 6,029,568 B of d_ws used

  prep_all<<<2576, 256, 0, stream>>>(enc, dec, Xb, Wf, WfF, Wb, bb, Wr, br, WoF, biasC);
  egemm<<<200, 256, 0, stream>>>(Xb, (const s16x8*)WfF, bf, Ebf, Dc);
  joint_main<<<2560, 256, 0, stream>>>(Ebf, Dc, (const s16x8*)WoF, biasC, out);
}